// Round 2
// baseline (1287.544 us; speedup 1.0000x reference)
//
#include <hip/hip_runtime.h>
#include <math.h>

// Problem: B=32, L1=L2=512, H=1024, fp32.
// out = concat(enhance(x1, x1~), enhance(x2, x2~)), enhance = [x, t, x-t, x*t].
//
// Pipeline (all fp32 vector for baseline correctness; MFMA split-bf16 comes later):
//   1. gemm_nt:            e[b,i,j] = sum_h x1[b,i,h] * x2[b,j,h]
//   2. col_stats(+combine): per (b,j) online max/sum over valid i   (for a21)
//   3. transpose_softmax:  p21[b,j,i] = softmax_i(e) with i-mask (tiled transpose)
//   4. row_softmax:        e <- softmax_j(e) with j-mask, IN PLACE (becomes p12)
//   5. gemm_nn_out(p12, x2, x1) -> out1 sections; gemm_nn_out(p21, x1, x2) -> out2
//
// ws usage: e (32 MB) + p21 (32 MB) + stats (~0.7 MB) = ~67.8 MB.

namespace {

constexpr int BATCH = 32;
constexpr int L = 512;
constexpr int H = 1024;
constexpr int OUTH = 4 * H;

constexpr int BM = 128;
constexpr int BN = 128;
constexpr int KT = 32;
constexpr int LDSP = BM + 4;  // 132: keeps float4 alignment, breaks pow2 bank stride

__device__ __forceinline__ float wave_max(float v) {
#pragma unroll
  for (int off = 32; off > 0; off >>= 1) v = fmaxf(v, __shfl_xor(v, off));
  return v;
}
__device__ __forceinline__ float wave_sum(float v) {
#pragma unroll
  for (int off = 32; off > 0; off >>= 1) v += __shfl_xor(v, off);
  return v;
}

// ---------------------------------------------------------------------------
// 1) C[b,m,n] = sum_k A[b,m,k] * Bm[b,n,k]    (A,Bm: [B][L][H], C: [B][L][L])
// ---------------------------------------------------------------------------
__global__ __launch_bounds__(256, 2)
void gemm_nt_kernel(const float* __restrict__ A, const float* __restrict__ Bm,
                    float* __restrict__ C) {
  __shared__ __align__(16) float As[KT][LDSP];
  __shared__ __align__(16) float Bs[KT][LDSP];
  const int b = blockIdx.z;
  const int m0 = blockIdx.x * BM;
  const int n0 = blockIdx.y * BN;
  const int tid = threadIdx.x;
  const float* Ab = A + (size_t)b * L * H + (size_t)m0 * H;
  const float* Bb = Bm + (size_t)b * L * H + (size_t)n0 * H;

  const int srow = tid >> 1;          // 0..127 staging row
  const int soff = (tid & 1) << 4;    // 0 or 16 (k offset)

  const int tm = tid & 15;
  const int tn = tid >> 4;

  float c[8][8];
#pragma unroll
  for (int i = 0; i < 8; ++i)
#pragma unroll
    for (int j = 0; j < 8; ++j) c[i][j] = 0.f;

  for (int k0 = 0; k0 < H; k0 += KT) {
    float4 av[4], bv[4];
    const float4* ap = (const float4*)(Ab + (size_t)srow * H + k0 + soff);
    const float4* bp = (const float4*)(Bb + (size_t)srow * H + k0 + soff);
#pragma unroll
    for (int q = 0; q < 4; ++q) av[q] = ap[q];
#pragma unroll
    for (int q = 0; q < 4; ++q) bv[q] = bp[q];
    __syncthreads();
#pragma unroll
    for (int q = 0; q < 4; ++q) {
      As[soff + q * 4 + 0][srow] = av[q].x;
      As[soff + q * 4 + 1][srow] = av[q].y;
      As[soff + q * 4 + 2][srow] = av[q].z;
      As[soff + q * 4 + 3][srow] = av[q].w;
      Bs[soff + q * 4 + 0][srow] = bv[q].x;
      Bs[soff + q * 4 + 1][srow] = bv[q].y;
      Bs[soff + q * 4 + 2][srow] = bv[q].z;
      Bs[soff + q * 4 + 3][srow] = bv[q].w;
    }
    __syncthreads();
#pragma unroll
    for (int k = 0; k < KT; ++k) {
      float a[8], bb[8];
      *(float4*)&a[0] = *(const float4*)&As[k][tm * 4];
      *(float4*)&a[4] = *(const float4*)&As[k][64 + tm * 4];
      *(float4*)&bb[0] = *(const float4*)&Bs[k][tn * 4];
      *(float4*)&bb[4] = *(const float4*)&Bs[k][64 + tn * 4];
#pragma unroll
      for (int i = 0; i < 8; ++i)
#pragma unroll
        for (int j = 0; j < 8; ++j) c[i][j] = fmaf(a[i], bb[j], c[i][j]);
    }
  }

  float* Cb = C + (size_t)b * L * L;
#pragma unroll
  for (int i = 0; i < 8; ++i) {
    const int m = m0 + ((i < 4) ? (tm * 4 + i) : (64 + tm * 4 + (i - 4)));
    float4 v0 = make_float4(c[i][0], c[i][1], c[i][2], c[i][3]);
    float4 v1 = make_float4(c[i][4], c[i][5], c[i][6], c[i][7]);
    *(float4*)(Cb + (size_t)m * L + n0 + tn * 4) = v0;
    *(float4*)(Cb + (size_t)m * L + n0 + 64 + tn * 4) = v1;
  }
}

// ---------------------------------------------------------------------------
// 2) per-(b,j) online max/sum over i chunks (for softmax over i, direction 2)
// ---------------------------------------------------------------------------
__global__ __launch_bounds__(256)
void col_stats_partial_kernel(const float* __restrict__ e, const int* __restrict__ len1,
                              float* __restrict__ pm, float* __restrict__ ps) {
  const int b = blockIdx.y;
  const int j = blockIdx.x * 256 + threadIdx.x;
  const int ch = blockIdx.z;
  const int n1 = len1[b];
  const int i0 = ch * (L / 4);
  const int i1 = min(n1, i0 + L / 4);
  const float* eb = e + (size_t)b * L * L + j;
  float m = -INFINITY, s = 0.f;
  for (int i = i0; i < i1; ++i) {
    float v = eb[(size_t)i * L];
    float nm = fmaxf(m, v);
    s = s * __expf(m - nm) + __expf(v - nm);
    m = nm;
  }
  const int idx = (ch * BATCH + b) * L + j;
  pm[idx] = m;
  ps[idx] = s;
}

__global__ __launch_bounds__(256)
void col_stats_combine_kernel(const float* __restrict__ pm, const float* __restrict__ ps,
                              float* __restrict__ cmax, float* __restrict__ crcp) {
  const int idx = blockIdx.x * 256 + threadIdx.x;  // b*L + j
  float m = -INFINITY;
#pragma unroll
  for (int c = 0; c < 4; ++c) m = fmaxf(m, pm[c * (BATCH * L) + idx]);
  float s = 0.f;
#pragma unroll
  for (int c = 0; c < 4; ++c) {
    float mc = pm[c * (BATCH * L) + idx];
    float sc = ps[c * (BATCH * L) + idx];
    s += (mc == -INFINITY) ? 0.f : sc * __expf(mc - m);
  }
  cmax[idx] = m;
  crcp[idx] = 1.f / s;
}

// ---------------------------------------------------------------------------
// 3) p21[b,j,i] = (i < n1) ? exp(e[b,i,j]-cmax[b,j]) * crcp[b,j] : 0
// ---------------------------------------------------------------------------
__global__ __launch_bounds__(256)
void transpose_softmax_kernel(const float* __restrict__ e, const float* __restrict__ cmax,
                              const float* __restrict__ crcp, const int* __restrict__ len1,
                              float* __restrict__ p21) {
  __shared__ float t[64][65];
  const int b = blockIdx.z;
  const int i0 = blockIdx.x << 6;
  const int j0 = blockIdx.y << 6;
  const int cc = threadIdx.x & 63;
  const int rr = threadIdx.x >> 6;
  const float* eb = e + (size_t)b * L * L;
#pragma unroll
  for (int ch = 0; ch < 16; ++ch) {
    const int r = (ch << 2) + rr;
    t[r][cc] = eb[(size_t)(i0 + r) * L + j0 + cc];
  }
  __syncthreads();
  const int n1 = len1[b];
  float* pb = p21 + (size_t)b * L * L;
#pragma unroll
  for (int ch = 0; ch < 16; ++ch) {
    const int r = (ch << 2) + rr;  // j offset within tile (wave-uniform)
    const int j = j0 + r;
    const float mj = cmax[b * L + j];
    const float rj = crcp[b * L + j];
    const int i = i0 + cc;
    const float val = (i < n1) ? __expf(t[cc][r] - mj) * rj : 0.f;
    pb[(size_t)j * L + i] = val;
  }
}

// ---------------------------------------------------------------------------
// 4) in-place row softmax over j with j-mask (e -> p12)
// ---------------------------------------------------------------------------
__global__ __launch_bounds__(256)
void row_softmax_kernel(float* __restrict__ e, const int* __restrict__ len2) {
  const int wave = (blockIdx.x << 2) + (threadIdx.x >> 6);
  const int lane = threadIdx.x & 63;
  const int b = wave >> 9;           // / L
  const int i = wave & (L - 1);
  const int n2 = len2[b];
  float* row = e + ((size_t)b * L + i) * L;
  float v[8];
  float m = -INFINITY;
#pragma unroll
  for (int q = 0; q < 8; ++q) {
    const int j = (q << 6) + lane;
    v[q] = row[j];
    if (j < n2) m = fmaxf(m, v[q]);
  }
  m = wave_max(m);
  float s = 0.f;
#pragma unroll
  for (int q = 0; q < 8; ++q) {
    const int j = (q << 6) + lane;
    v[q] = (j < n2) ? __expf(v[q] - m) : 0.f;
    s += v[q];
  }
  s = wave_sum(s);
  const float r = 1.f / s;
#pragma unroll
  for (int q = 0; q < 8; ++q) row[(q << 6) + lane] = v[q] * r;
}

// ---------------------------------------------------------------------------
// 5) C = P(LxL) @ X(LxH); fused enhance epilogue:
//    Out[b, m, 0:H]=Xbar, [H:2H]=C, [2H:3H]=Xbar-C, [3H:4H]=Xbar*C
// ---------------------------------------------------------------------------
__global__ __launch_bounds__(256, 2)
void gemm_nn_out_kernel(const float* __restrict__ P, const float* __restrict__ X,
                        const float* __restrict__ Xbar, float* __restrict__ Out) {
  __shared__ __align__(16) float As[KT][LDSP];  // As[k][m]
  __shared__ __align__(16) float Bs[KT][LDSP];  // Bs[k][n]
  const int b = blockIdx.z;
  const int m0 = blockIdx.x * BM;
  const int n0 = blockIdx.y * BN;
  const int tid = threadIdx.x;
  const float* Pb = P + (size_t)b * L * L + (size_t)m0 * L;
  const float* Xb = X + (size_t)b * L * H;

  const int srow = tid >> 1;          // A staging row (0..127)
  const int soff = (tid & 1) << 4;    // k offset 0/16
  const int bk = tid & 31;            // B staging k-row
  const int bseg = (tid >> 5) << 4;   // n offset 0,16,...,112

  const int tm = tid & 15;
  const int tn = tid >> 4;

  float c[8][8];
#pragma unroll
  for (int i = 0; i < 8; ++i)
#pragma unroll
    for (int j = 0; j < 8; ++j) c[i][j] = 0.f;

  for (int k0 = 0; k0 < L; k0 += KT) {
    float4 av[4], bv[4];
    const float4* ap = (const float4*)(Pb + (size_t)srow * L + k0 + soff);
    const float4* bp = (const float4*)(Xb + (size_t)(k0 + bk) * H + n0 + bseg);
#pragma unroll
    for (int q = 0; q < 4; ++q) av[q] = ap[q];
#pragma unroll
    for (int q = 0; q < 4; ++q) bv[q] = bp[q];
    __syncthreads();
#pragma unroll
    for (int q = 0; q < 4; ++q) {
      As[soff + q * 4 + 0][srow] = av[q].x;
      As[soff + q * 4 + 1][srow] = av[q].y;
      As[soff + q * 4 + 2][srow] = av[q].z;
      As[soff + q * 4 + 3][srow] = av[q].w;
    }
#pragma unroll
    for (int q = 0; q < 4; ++q) *(float4*)&Bs[bk][bseg + q * 4] = bv[q];
    __syncthreads();
#pragma unroll
    for (int k = 0; k < KT; ++k) {
      float a[8], bb[8];
      *(float4*)&a[0] = *(const float4*)&As[k][tm * 4];
      *(float4*)&a[4] = *(const float4*)&As[k][64 + tm * 4];
      *(float4*)&bb[0] = *(const float4*)&Bs[k][tn * 4];
      *(float4*)&bb[4] = *(const float4*)&Bs[k][64 + tn * 4];
#pragma unroll
      for (int i = 0; i < 8; ++i)
#pragma unroll
        for (int j = 0; j < 8; ++j) c[i][j] = fmaf(a[i], bb[j], c[i][j]);
    }
  }

  const float* XbarB = Xbar + (size_t)b * L * H;
  float* OutB = Out + (size_t)b * L * OUTH;
#pragma unroll
  for (int i = 0; i < 8; ++i) {
    const int m = m0 + ((i < 4) ? (tm * 4 + i) : (64 + tm * 4 + (i - 4)));
    const float* xr = XbarB + (size_t)m * H;
    float* orow = OutB + (size_t)m * OUTH;
    const int na = n0 + tn * 4;
    const int nb = n0 + 64 + tn * 4;
    const float4 xb0 = *(const float4*)(xr + na);
    const float4 xb1 = *(const float4*)(xr + nb);
    const float4 t0 = make_float4(c[i][0], c[i][1], c[i][2], c[i][3]);
    const float4 t1 = make_float4(c[i][4], c[i][5], c[i][6], c[i][7]);
    *(float4*)(orow + na) = xb0;
    *(float4*)(orow + nb) = xb1;
    *(float4*)(orow + H + na) = t0;
    *(float4*)(orow + H + nb) = t1;
    *(float4*)(orow + 2 * H + na) = make_float4(xb0.x - t0.x, xb0.y - t0.y, xb0.z - t0.z, xb0.w - t0.w);
    *(float4*)(orow + 2 * H + nb) = make_float4(xb1.x - t1.x, xb1.y - t1.y, xb1.z - t1.z, xb1.w - t1.w);
    *(float4*)(orow + 3 * H + na) = make_float4(xb0.x * t0.x, xb0.y * t0.y, xb0.z * t0.z, xb0.w * t0.w);
    *(float4*)(orow + 3 * H + nb) = make_float4(xb1.x * t1.x, xb1.y * t1.y, xb1.z * t1.z, xb1.w * t1.w);
  }
}

}  // namespace

extern "C" void kernel_launch(void* const* d_in, const int* in_sizes, int n_in,
                              void* d_out, int out_size, void* d_ws, size_t ws_size,
                              hipStream_t stream) {
  (void)in_sizes; (void)n_in; (void)out_size; (void)ws_size;
  const float* x1 = (const float*)d_in[0];
  const int* len1 = (const int*)d_in[1];
  const float* x2 = (const float*)d_in[2];
  const int* len2 = (const int*)d_in[3];
  float* out = (float*)d_out;

  float* ws = (float*)d_ws;
  const size_t EL = (size_t)BATCH * L * L;  // 8,388,608 floats
  float* e = ws;                            // [B][L][L], later becomes p12 in place
  float* p21 = ws + EL;                     // [B][L2][L1]
  float* pm = ws + 2 * EL;                  // [4][B][L]
  float* psv = pm + 4 * BATCH * L;          // [4][B][L]
  float* cm = psv + 4 * BATCH * L;          // [B][L]
  float* cr = cm + BATCH * L;               // [B][L]

  const dim3 blk(256);

  // 1) e = x1 @ x2^T
  gemm_nt_kernel<<<dim3(L / BM, L / BN, BATCH), blk, 0, stream>>>(x1, x2, e);
  // 2) column stats over i (for a21)
  col_stats_partial_kernel<<<dim3(L / 256, BATCH, 4), blk, 0, stream>>>(e, len1, pm, psv);
  col_stats_combine_kernel<<<dim3(BATCH * L / 256), blk, 0, stream>>>(pm, psv, cm, cr);
  // 3) p21 = softmax_i(e)^T (transposed layout)
  transpose_softmax_kernel<<<dim3(L / 64, L / 64, BATCH), blk, 0, stream>>>(e, cm, cr, len1, p21);
  // 4) e <- softmax_j(e) in place (p12)
  row_softmax_kernel<<<dim3(BATCH * L / 4), blk, 0, stream>>>(e, len2);
  // 5) out1 = enhance(x1, p12 @ x2); out2 = enhance(x2, p21 @ x1)
  gemm_nn_out_kernel<<<dim3(L / BM, H / BN, BATCH), blk, 0, stream>>>(e, x2, x1, out);
  gemm_nn_out_kernel<<<dim3(L / BM, H / BN, BATCH), blk, 0, stream>>>(
      p21, x1, x2, out + (size_t)BATCH * L * OUTH);
}

// Round 3
// 1071.263 us; speedup vs baseline: 1.2019x; 1.2019x over previous
//
#include <hip/hip_runtime.h>
#include <hip/hip_bf16.h>
#include <math.h>

// B=32, L1=L2=512, H=1024, fp32 in/out.
// Split-bf16 MFMA pipeline:
//   convert:      x -> (hi,lo) bf16 planes, natural [L][H] and transposed [H][L]
//   egemm:        e = x1 . x2^T   (3-term split MFMA, NT, 128x128 tile)
//   col_stats:    per-(b,j) max/sum over valid i  (softmax over i)
//   tsoftmax:     p21[b,j,i] (hi/lo bf16 planes)
//   rsoftmax:     p12[b,i,j] (hi/lo bf16 planes)
//   ogemm:        out1 = enhance(x1, p12 @ x2), out2 = enhance(x2, p21 @ x1)
//                 (NT vs pre-transposed X, fused 4-section epilogue)

namespace {

constexpr int BATCH = 32;
constexpr int L = 512;
constexpr int H = 1024;
constexpr int OUTH = 4 * H;
constexpr size_t NLH = (size_t)BATCH * L * H;   // 16,777,216
constexpr size_t NLL = (size_t)BATCH * L * L;   //  8,388,608

typedef short bf16x8 __attribute__((ext_vector_type(8)));
typedef float f32x4 __attribute__((ext_vector_type(4)));

__device__ __forceinline__ void split_bf16(float v, short& h, short& l) {
  __hip_bfloat16 bh = __float2bfloat16(v);
  float r = v - __bfloat162float(bh);
  __hip_bfloat16 bl = __float2bfloat16(r);
  h = __builtin_bit_cast(short, bh);
  l = __builtin_bit_cast(short, bl);
}

__device__ __forceinline__ void gload_lds16(const short* g, short* l) {
  __builtin_amdgcn_global_load_lds((const __attribute__((address_space(1))) void*)g,
                                   (__attribute__((address_space(3))) void*)l, 16, 0, 0);
}

__device__ __forceinline__ float wave_max(float v) {
#pragma unroll
  for (int off = 32; off > 0; off >>= 1) v = fmaxf(v, __shfl_xor(v, off));
  return v;
}
__device__ __forceinline__ float wave_sum(float v) {
#pragma unroll
  for (int off = 32; off > 0; off >>= 1) v += __shfl_xor(v, off);
  return v;
}

// ---------------------------------------------------------------------------
// convert: fp32 [N*8] -> hi/lo bf16 planes (natural layout)
// ---------------------------------------------------------------------------
__global__ __launch_bounds__(256)
void convert_kernel(const float* __restrict__ x, short* __restrict__ hi,
                    short* __restrict__ lo) {
  const size_t t = (size_t)blockIdx.x * 256 + threadIdx.x;
  const float4 a = *((const float4*)x + t * 2);
  const float4 b = *((const float4*)x + t * 2 + 1);
  const float vs[8] = {a.x, a.y, a.z, a.w, b.x, b.y, b.z, b.w};
  bf16x8 hv, lv;
#pragma unroll
  for (int e = 0; e < 8; ++e) {
    short hs, ls;
    split_bf16(vs[e], hs, ls);
    hv[e] = hs;
    lv[e] = ls;
  }
  *(bf16x8*)(hi + t * 8) = hv;
  *(bf16x8*)(lo + t * 8) = lv;
}

// ---------------------------------------------------------------------------
// convert+transpose: x [B][L][H] fp32 -> xT hi/lo [B][H][L] bf16
// ---------------------------------------------------------------------------
__global__ __launch_bounds__(256)
void convt_kernel(const float* __restrict__ x, short* __restrict__ hiT,
                  short* __restrict__ loT) {
  __shared__ float t[64][65];
  const int b = blockIdx.z;
  const int l0 = blockIdx.x << 6;
  const int h0 = blockIdx.y << 6;
  const int c = threadIdx.x & 63;
  const int rr = threadIdx.x >> 6;
  const float* xb = x + (size_t)b * L * H;
#pragma unroll
  for (int q = 0; q < 16; ++q) {
    const int r = (q << 2) + rr;
    t[r][c] = xb[(size_t)(l0 + r) * H + h0 + c];
  }
  __syncthreads();
  const int hr = threadIdx.x >> 2;   // h-row within tile
  const int c2 = threadIdx.x & 3;    // 16-wide l chunk
  bf16x8 h0v, h1v, l0v, l1v;
#pragma unroll
  for (int e = 0; e < 16; ++e) {
    short hs, ls;
    split_bf16(t[c2 * 16 + e][hr], hs, ls);
    if (e < 8) { h0v[e] = hs; l0v[e] = ls; }
    else       { h1v[e - 8] = hs; l1v[e - 8] = ls; }
  }
  const size_t ob = (size_t)b * H * L + (size_t)(h0 + hr) * L + l0 + c2 * 16;
  *(bf16x8*)(hiT + ob) = h0v;
  *(bf16x8*)(hiT + ob + 8) = h1v;
  *(bf16x8*)(loT + ob) = l0v;
  *(bf16x8*)(loT + ob + 8) = l1v;
}

// ---------------------------------------------------------------------------
// shared MFMA core: 128x128 tile, BK=32, 4 waves (2x2 of 64x64), NT operands,
// 3-term split accumulation. lds = 4 x 4096 shorts {Ahi, Alo, Bhi, Blo}.
// ---------------------------------------------------------------------------
template <int KSTEPS>
__device__ __forceinline__ void gemm_core(const short* __restrict__ Ahi,
                                          const short* __restrict__ Alo, int lda,
                                          int arow0, const short* __restrict__ Bhi,
                                          const short* __restrict__ Blo, int ldb,
                                          int brow0, short* lds, f32x4 (&acc)[4][4],
                                          int wr, int wc, int lane, int wave) {
  const int rsub = lane >> 2;         // row within 16-row chunk
  const int ksub = (lane & 3) * 8;    // k elem offset within row
  const int fr = lane & 15;
  const int ko = (lane >> 4) * 8;
  for (int ks = 0; ks < KSTEPS; ++ks) {
    const int k0 = ks * 32;
    __syncthreads();  // WAR: previous compute done before restage
#pragma unroll
    for (int b2 = 0; b2 < 4; ++b2) {
#pragma unroll
      for (int s2 = 0; s2 < 2; ++s2) {
        const int sub = s2 * 4 + wave;
        const int row = sub * 16 + rsub;
        const short* g;
        if (b2 == 0)      g = Ahi + (size_t)(arow0 + row) * lda + k0 + ksub;
        else if (b2 == 1) g = Alo + (size_t)(arow0 + row) * lda + k0 + ksub;
        else if (b2 == 2) g = Bhi + (size_t)(brow0 + row) * ldb + k0 + ksub;
        else              g = Blo + (size_t)(brow0 + row) * ldb + k0 + ksub;
        gload_lds16(g, lds + b2 * 4096 + sub * 512);
      }
    }
    __syncthreads();  // drains vmcnt -> tiles visible
    bf16x8 ah[4], al[4], bh[4], bl[4];
#pragma unroll
    for (int q = 0; q < 4; ++q) {
      const int ar = wr * 64 + q * 16 + fr;
      const int br = wc * 64 + q * 16 + fr;
      ah[q] = *(const bf16x8*)(lds + 0 * 4096 + ar * 32 + ko);
      al[q] = *(const bf16x8*)(lds + 1 * 4096 + ar * 32 + ko);
      bh[q] = *(const bf16x8*)(lds + 2 * 4096 + br * 32 + ko);
      bl[q] = *(const bf16x8*)(lds + 3 * 4096 + br * 32 + ko);
    }
#pragma unroll
    for (int q = 0; q < 4; ++q)
#pragma unroll
      for (int r = 0; r < 4; ++r) {
        acc[q][r] = __builtin_amdgcn_mfma_f32_16x16x32_bf16(ah[q], bh[r], acc[q][r], 0, 0, 0);
        acc[q][r] = __builtin_amdgcn_mfma_f32_16x16x32_bf16(ah[q], bl[r], acc[q][r], 0, 0, 0);
        acc[q][r] = __builtin_amdgcn_mfma_f32_16x16x32_bf16(al[q], bh[r], acc[q][r], 0, 0, 0);
      }
  }
}

// ---------------------------------------------------------------------------
// e[b,i,j] = x1[b,i,:] . x2[b,j,:]
// ---------------------------------------------------------------------------
__global__ __launch_bounds__(256, 2)
void egemm_kernel(const short* __restrict__ x1h, const short* __restrict__ x1l,
                  const short* __restrict__ x2h, const short* __restrict__ x2l,
                  float* __restrict__ e) {
  __shared__ short lds[4 * 4096];
  const int b = blockIdx.z;
  const int m0 = blockIdx.x * 128;
  const int n0 = blockIdx.y * 128;
  const int lane = threadIdx.x & 63;
  const int wave = threadIdx.x >> 6;
  const int wr = wave >> 1, wc = wave & 1;
  f32x4 acc[4][4] = {};
  const size_t ib = (size_t)b * L * H;
  gemm_core<H / 32>(x1h + ib, x1l + ib, H, m0, x2h + ib, x2l + ib, H, n0, lds, acc,
                    wr, wc, lane, wave);
  float* eb = e + (size_t)b * L * L;
  const int cr = (lane >> 4) * 4;
  const int cc = lane & 15;
#pragma unroll
  for (int q = 0; q < 4; ++q)
#pragma unroll
    for (int r = 0; r < 4; ++r)
#pragma unroll
      for (int v = 0; v < 4; ++v)
        eb[(size_t)(m0 + wr * 64 + q * 16 + cr + v) * L + n0 + wc * 64 + r * 16 + cc] =
            acc[q][r][v];
}

// ---------------------------------------------------------------------------
// col stats over i (for softmax over i)
// ---------------------------------------------------------------------------
__global__ __launch_bounds__(256)
void col_stats_partial_kernel(const float* __restrict__ e, const int* __restrict__ len1,
                              float* __restrict__ pm, float* __restrict__ ps) {
  const int b = blockIdx.y;
  const int j = blockIdx.x * 256 + threadIdx.x;
  const int ch = blockIdx.z;
  const int n1 = len1[b];
  const int i0 = ch * (L / 4);
  const int i1 = min(n1, i0 + L / 4);
  const float* eb = e + (size_t)b * L * L + j;
  float m = -INFINITY, s = 0.f;
  for (int i = i0; i < i1; ++i) {
    float v = eb[(size_t)i * L];
    float nm = fmaxf(m, v);
    s = s * __expf(m - nm) + __expf(v - nm);
    m = nm;
  }
  const int idx = (ch * BATCH + b) * L + j;
  pm[idx] = m;
  ps[idx] = s;
}

__global__ __launch_bounds__(256)
void col_stats_combine_kernel(const float* __restrict__ pm, const float* __restrict__ ps,
                              float* __restrict__ cmax, float* __restrict__ crcp) {
  const int idx = blockIdx.x * 256 + threadIdx.x;
  float m = -INFINITY;
#pragma unroll
  for (int c = 0; c < 4; ++c) m = fmaxf(m, pm[c * (BATCH * L) + idx]);
  float s = 0.f;
#pragma unroll
  for (int c = 0; c < 4; ++c) {
    float mc = pm[c * (BATCH * L) + idx];
    float sc = ps[c * (BATCH * L) + idx];
    s += (mc == -INFINITY) ? 0.f : sc * __expf(mc - m);
  }
  cmax[idx] = m;
  crcp[idx] = 1.f / s;
}

// ---------------------------------------------------------------------------
// p21[b,j,i] hi/lo = softmax_i(e)^T  (64x64 LDS transpose tiles)
// ---------------------------------------------------------------------------
__global__ __launch_bounds__(256)
void tsoftmax_kernel(const float* __restrict__ e, const float* __restrict__ cmax,
                     const float* __restrict__ crcp, const int* __restrict__ len1,
                     short* __restrict__ p21h, short* __restrict__ p21l) {
  __shared__ float t[64][65];
  const int b = blockIdx.z;
  const int i0 = blockIdx.x << 6;
  const int j0 = blockIdx.y << 6;
  const int c = threadIdx.x & 63;
  const int rr = threadIdx.x >> 6;
  const float* eb = e + (size_t)b * L * L;
#pragma unroll
  for (int q = 0; q < 16; ++q) {
    const int r = (q << 2) + rr;
    t[r][c] = eb[(size_t)(i0 + r) * L + j0 + c];
  }
  __syncthreads();
  const int n1 = len1[b];
  const int jr = threadIdx.x >> 2;
  const int c2 = threadIdx.x & 3;
  const int j = j0 + jr;
  const float mj = cmax[b * L + j];
  const float rj = crcp[b * L + j];
  bf16x8 h0v, h1v, l0v, l1v;
#pragma unroll
  for (int e2 = 0; e2 < 16; ++e2) {
    const int i = i0 + c2 * 16 + e2;
    const float p = (i < n1) ? __expf(t[c2 * 16 + e2][jr] - mj) * rj : 0.f;
    short hs, ls;
    split_bf16(p, hs, ls);
    if (e2 < 8) { h0v[e2] = hs; l0v[e2] = ls; }
    else        { h1v[e2 - 8] = hs; l1v[e2 - 8] = ls; }
  }
  const size_t ob = (size_t)b * L * L + (size_t)j * L + i0 + c2 * 16;
  *(bf16x8*)(p21h + ob) = h0v;
  *(bf16x8*)(p21h + ob + 8) = h1v;
  *(bf16x8*)(p21l + ob) = l0v;
  *(bf16x8*)(p21l + ob + 8) = l1v;
}

// ---------------------------------------------------------------------------
// p12[b,i,j] hi/lo = softmax_j(e), one wave per row, lane owns 8 consecutive j
// ---------------------------------------------------------------------------
__global__ __launch_bounds__(256)
void rsoftmax_kernel(const float* __restrict__ e, const int* __restrict__ len2,
                     short* __restrict__ p12h, short* __restrict__ p12l) {
  const int wave = (blockIdx.x << 2) + (threadIdx.x >> 6);
  const int lane = threadIdx.x & 63;
  const int b = wave >> 9;
  const int i = wave & (L - 1);
  const int n2 = len2[b];
  const size_t rowb = ((size_t)b * L + i) * L;
  const float4 a = *(const float4*)(e + rowb + lane * 8);
  const float4 c = *(const float4*)(e + rowb + lane * 8 + 4);
  float v[8] = {a.x, a.y, a.z, a.w, c.x, c.y, c.z, c.w};
  float m = -INFINITY;
#pragma unroll
  for (int q = 0; q < 8; ++q)
    if (lane * 8 + q < n2) m = fmaxf(m, v[q]);
  m = wave_max(m);
  float s = 0.f;
#pragma unroll
  for (int q = 0; q < 8; ++q) {
    v[q] = (lane * 8 + q < n2) ? __expf(v[q] - m) : 0.f;
    s += v[q];
  }
  s = wave_sum(s);
  const float r = 1.f / s;
  bf16x8 hv, lv;
#pragma unroll
  for (int q = 0; q < 8; ++q) {
    short hs, ls;
    split_bf16(v[q] * r, hs, ls);
    hv[q] = hs;
    lv[q] = ls;
  }
  *(bf16x8*)(p12h + rowb + lane * 8) = hv;
  *(bf16x8*)(p12l + rowb + lane * 8) = lv;
}

// ---------------------------------------------------------------------------
// out = enhance(Xbar, P @ X):  A = P [L][L] hi/lo, B = XT [H][L] hi/lo (NT)
// ---------------------------------------------------------------------------
__global__ __launch_bounds__(256, 2)
void ogemm_kernel(const short* __restrict__ ph, const short* __restrict__ pl,
                  const short* __restrict__ xth, const short* __restrict__ xtl,
                  const float* __restrict__ xbar, float* __restrict__ outp) {
  __shared__ short lds[4 * 4096];
  const int b = blockIdx.z;
  const int m0 = blockIdx.x * 128;
  const int n0 = blockIdx.y * 128;
  const int lane = threadIdx.x & 63;
  const int wave = threadIdx.x >> 6;
  const int wr = wave >> 1, wc = wave & 1;
  f32x4 acc[4][4] = {};
  gemm_core<L / 32>(ph + (size_t)b * L * L, pl + (size_t)b * L * L, L, m0,
                    xth + (size_t)b * H * L, xtl + (size_t)b * H * L, L, n0, lds, acc,
                    wr, wc, lane, wave);
  const float* xbb = xbar + (size_t)b * L * H;
  float* ob = outp + (size_t)b * L * OUTH;
  const int cr = (lane >> 4) * 4;
  const int cc = lane & 15;
#pragma unroll
  for (int q = 0; q < 4; ++q)
#pragma unroll
    for (int r = 0; r < 4; ++r)
#pragma unroll
      for (int v = 0; v < 4; ++v) {
        const int i = m0 + wr * 64 + q * 16 + cr + v;
        const int h = n0 + wc * 64 + r * 16 + cc;
        const float xb = xbb[(size_t)i * H + h];
        const float tv = acc[q][r][v];
        float* orow = ob + (size_t)i * OUTH;
        orow[h] = xb;
        orow[H + h] = tv;
        orow[2 * H + h] = xb - tv;
        orow[3 * H + h] = xb * tv;
      }
}

}  // namespace

extern "C" void kernel_launch(void* const* d_in, const int* in_sizes, int n_in,
                              void* d_out, int out_size, void* d_ws, size_t ws_size,
                              hipStream_t stream) {
  (void)in_sizes; (void)n_in; (void)out_size; (void)ws_size;
  const float* x1 = (const float*)d_in[0];
  const int* len1 = (const int*)d_in[1];
  const float* x2 = (const float*)d_in[2];
  const int* len2 = (const int*)d_in[3];
  float* out = (float*)d_out;

  // workspace layout (~370 MB; ws is ~2 GiB per harness fill evidence)
  short* wsS = (short*)d_ws;
  short* x1h = wsS;                 // NLH shorts each
  short* x1l = x1h + NLH;
  short* x2h = x1l + NLH;
  short* x2l = x2h + NLH;
  short* x1Th = x2l + NLH;          // transposed [B][H][L]
  short* x1Tl = x1Th + NLH;
  short* x2Th = x1Tl + NLH;
  short* x2Tl = x2Th + NLH;
  float* e = (float*)(x2Tl + NLH);  // NLL floats
  short* p12h = (short*)(e + NLL);  // NLL shorts each
  short* p12l = p12h + NLL;
  short* p21h = p12l + NLL;
  short* p21l = p21h + NLL;
  float* pm = (float*)(p21l + NLL); // [4][B][L]
  float* psv = pm + 4 * BATCH * L;
  float* cm = psv + 4 * BATCH * L;
  float* cr = cm + BATCH * L;

  const dim3 blk(256);
  const int cvtBlocks = (int)(NLH / 8 / 256);  // 8192

  convert_kernel<<<cvtBlocks, blk, 0, stream>>>(x1, x1h, x1l);
  convert_kernel<<<cvtBlocks, blk, 0, stream>>>(x2, x2h, x2l);
  convt_kernel<<<dim3(L / 64, H / 64, BATCH), blk, 0, stream>>>(x1, x1Th, x1Tl);
  convt_kernel<<<dim3(L / 64, H / 64, BATCH), blk, 0, stream>>>(x2, x2Th, x2Tl);

  egemm_kernel<<<dim3(L / 128, L / 128, BATCH), blk, 0, stream>>>(x1h, x1l, x2h, x2l, e);

  col_stats_partial_kernel<<<dim3(L / 256, BATCH, 4), blk, 0, stream>>>(e, len1, pm, psv);
  col_stats_combine_kernel<<<dim3(BATCH * L / 256), blk, 0, stream>>>(pm, psv, cm, cr);
  tsoftmax_kernel<<<dim3(L / 64, L / 64, BATCH), blk, 0, stream>>>(e, cm, cr, len1, p21h, p21l);
  rsoftmax_kernel<<<dim3(BATCH * L / 4), blk, 0, stream>>>(e, len2, p12h, p12l);

  ogemm_kernel<<<dim3(L / 128, H / 128, BATCH), blk, 0, stream>>>(p12h, p12l, x2Th, x2Tl, x1, out);
  ogemm_kernel<<<dim3(L / 128, H / 128, BATCH), blk, 0, stream>>>(p21h, p21l, x1Th, x1Tl, x2,
                                                                  out + NLH * 4);
}